// Round 7
// baseline (119.682 us; speedup 1.0000x reference)
//
#include <hip/hip_runtime.h>
#include <math.h>

#define HH 256
#define WW 256
#define NG 714
#define NROWS 768          // padded to 3x256 prep grid; pad rows always culled
#define NGP4 716           // s_tz padded for float4 rank loop
#define FOCALF 128.0f
#define EPS2D_F 0.3f
#define ALPHA_MIN_F (1.0f/255.0f)
#define CAM_T_F 8.0f
#define LOG2E_F 1.4426950408889634f
#define PR 12              // floats/row: [mx,my,A2n,B2n][C2n,K,cr,cg][cb,e,f,thr]
#define T_EPS 0.003f       // early-termination bound (error <= eps per channel)

// Kernel 1: projection + conic + stable depth rank + scatter into sorted rows.
// Conic stored NEGATED, prefolded with log2(e); K = log2(op) folded additively:
// sg = A2n*dx^2 + B2n*dx*dy + C2n*dy^2 + K  ->  alpha = exp2(sg) = op*exp(-sigma).
// Cull fields: e = C-B^2/4A, f = A-B^2/4C (positive conic, >=0);
// gaussian irrelevant for a box iff max(e*dymin^2, f*dxmin^2) > thr = log2(255)+K
// (then alpha < 1/255 for EVERY pixel in the box -> reference zeroes it: EXACT cull).
__global__ __launch_bounds__(256) void gs_prep(
    const float* __restrict__ means, const float* __restrict__ quats,
    const float* __restrict__ scales, const float* __restrict__ opacities,
    const float* __restrict__ rgbs, float* __restrict__ params)
{
    __shared__ float s_tz[NGP4];
    const int lane = threadIdx.x;
    const int i = blockIdx.x * 256 + lane;

    for (int j = lane; j < NGP4; j += 256)
        s_tz[j] = (j < NG) ? (means[3*j+2] + CAM_T_F) : INFINITY;
    __syncthreads();

    if (i >= NROWS) return;
    if (i >= NG) {                      // pad rows: always culled (0 > thr=-1)
        float4* row = (float4*)(params + i*PR);
        row[0] = make_float4(0.f,0.f,0.f,0.f);
        row[1] = make_float4(0.f,0.f,0.f,0.f);
        row[2] = make_float4(0.f,0.f,0.f,-1.f);
        return;
    }

    float m0 = means[i*3+0], m1 = means[i*3+1];
    float tz = s_tz[i];
    float qw = quats[i*4+0], qx = quats[i*4+1], qy = quats[i*4+2], qz = quats[i*4+3];
    float qn = rsqrtf(qw*qw + qx*qx + qy*qy + qz*qz);
    qw*=qn; qx*=qn; qy*=qn; qz*=qn;
    float sx = scales[i*3+0], sy = scales[i*3+1], sz = scales[i*3+2];
    float s0 = sx*sx, s1 = sy*sy, s2 = sz*sz;
    float R00 = 1.f-2.f*(qy*qy+qz*qz), R01 = 2.f*(qx*qy-qw*qz), R02 = 2.f*(qx*qz+qw*qy);
    float R10 = 2.f*(qx*qy+qw*qz),     R11 = 1.f-2.f*(qx*qx+qz*qz), R12 = 2.f*(qy*qz-qw*qx);
    float R20 = 2.f*(qx*qz-qw*qy),     R21 = 2.f*(qy*qz+qw*qx),     R22 = 1.f-2.f*(qx*qx+qy*qy);
    float S00 = R00*R00*s0 + R01*R01*s1 + R02*R02*s2;
    float S01 = R00*R10*s0 + R01*R11*s1 + R02*R12*s2;
    float S02 = R00*R20*s0 + R01*R21*s1 + R02*R22*s2;
    float S11 = R10*R10*s0 + R11*R11*s1 + R12*R12*s2;
    float S12 = R10*R20*s0 + R11*R21*s1 + R12*R22*s2;
    float S22 = R20*R20*s0 + R21*R21*s1 + R22*R22*s2;
    float inv = 1.f/tz;
    float mx = FOCALF*m0*inv + 0.5f*WW;
    float my = FOCALF*m1*inv + 0.5f*HH;
    float j0 = FOCALF*inv;
    float j2 = -FOCALF*m0*inv*inv;
    float j5 = -FOCALF*m1*inv*inv;
    float a = j0*j0*S00 + 2.f*j0*j2*S02 + j2*j2*S22 + EPS2D_F;
    float b = j0*(j0*S01 + j2*S12) + j5*(j0*S02 + j2*S22);
    float c = j0*j0*S11 + 2.f*j0*j5*S12 + j5*j5*S22 + EPS2D_F;
    float det = a*c - b*b;
    float idet = 1.f/det;
    float hA = 0.5f*c*idet*LOG2E_F;      // positive conic terms (log2-scaled)
    float Bc = -b*idet*LOG2E_F;
    float hC = 0.5f*a*idet*LOG2E_F;
    float e  = hC - Bc*Bc/(4.f*hA);      // min over dx of sigma' = e*dy^2
    float f  = hA - Bc*Bc/(4.f*hC);      // min over dy of sigma' = f*dx^2
    float op = 1.f/(1.f+__expf(-opacities[i]));
    float K  = log2f(op);                // folded into exponent
    float thr = log2f(255.f) + K;        // cull iff bound > thr
    float cr = 1.f/(1.f+__expf(-rgbs[i*3+0]));
    float cg = 1.f/(1.f+__expf(-rgbs[i*3+1]));
    float cb = 1.f/(1.f+__expf(-rgbs[i*3+2]));

    const float4* t4 = (const float4*)s_tz;
    int rank = 0;
    #pragma unroll 4
    for (int jj = 0; jj < NGP4/4; ++jj) {
        float4 v = t4[jj];
        int j = 4*jj;
        rank += (v.x < tz) || (v.x == tz && (j+0) < i);
        rank += (v.y < tz) || (v.y == tz && (j+1) < i);
        rank += (v.z < tz) || (v.z == tz && (j+2) < i);
        rank += (v.w < tz) || (v.w == tz && (j+3) < i);
    }

    float4* row = (float4*)(params + rank*PR);
    row[0] = make_float4(mx, my, -hA, -Bc);
    row[1] = make_float4(-hC, K, cr, cg);
    row[2] = make_float4(cb, e, f, thr);
}

// Kernel 2: fused bin+composite. Block = one 16x16 tile, 1024 threads.
// Phase A: 768 threads test one sorted row each against the tile box (EXACT
// cull) and ballot+prefix-compact survivors (depth order) into LDS.
// Phase B: 16 waves = 4 pixel-quadrants (16x4) x 4 depth segments over the
// compact list; thread = 1 px. Wave-local T-collapse publishes its absolute
// list position to s_dead[quadrant]; later-segment waves poll and exit
// (bounded error < T_EPS). Phase C: per-quadrant in-order segment reduce.
__global__ __launch_bounds__(1024, 1) void gs_composite(
    const float* __restrict__ params, float* __restrict__ out)
{
    __shared__ float4 s_list[NG*3];      // 34.3 KB compact rows
    __shared__ float4 s_part[16][64];    // 16 KB segment partials
    __shared__ int s_wcnt[12];
    __shared__ int s_cnt;
    __shared__ int s_dead[4];

    const int t = threadIdx.x;
    const int lane = t & 63;
    const int wv = t >> 6;               // 0..15
    const int x0 = (blockIdx.x & 15) * 16;
    const int y0 = (blockIdx.x >> 4) * 16;
    const float xc = (float)x0 + 8.0f;   // box center, half-span 7.5
    const float yc = (float)y0 + 8.0f;

    // ---- Phase A: scan + ordered compaction into LDS ----
    bool keep = false;
    float4 q0, q1, q2;
    if (t < NROWS) {
        const float4* src = (const float4*)params + 3*t;
        q0 = src[0]; q1 = src[1]; q2 = src[2];
        float dymin = fmaxf(fabsf(yc - q0.y) - 7.5f, 0.f);
        float dxmin = fmaxf(fabsf(xc - q0.x) - 7.5f, 0.f);
        keep = !(fmaxf(q2.y*dymin*dymin, q2.z*dxmin*dxmin) > q2.w);
    }
    unsigned long long bal = __ballot(keep);
    if (t < NROWS && lane == 0) s_wcnt[wv] = (int)__popcll(bal);
    if (t < 4) s_dead[t] = 0x7fffffff;
    __syncthreads();
    if (keep) {
        int pos = (int)__popcll(bal & ((1ull << lane) - 1ull));
        for (int w = 0; w < wv; ++w) pos += s_wcnt[w];
        s_list[pos*3+0] = q0; s_list[pos*3+1] = q1; s_list[pos*3+2] = q2;
    }
    if (t == 0) {
        int L = 0;
        #pragma unroll
        for (int w = 0; w < 12; ++w) L += s_wcnt[w];
        s_cnt = L;
    }
    __syncthreads();

    // ---- Phase B: composite over compact list ----
    const int qd = wv & 3;               // pixel quadrant (rows y0+4qd..+3)
    const int sgi = wv >> 2;             // depth segment
    const int L = s_cnt;
    const int chunk = (L + 3) >> 2;
    const int c0 = sgi * chunk;
    const int c1 = min(c0 + chunk, L);
    const float px = (float)(x0 + (lane & 15)) + 0.5f;
    const float py = (float)(y0 + qd*4 + (lane >> 4)) + 0.5f;

    float T = 1.f, rr = 0.f, gg = 0.f, bb = 0.f;
    for (int n = c0; n < c1; ++n) {
        if (__builtin_amdgcn_readfirstlane(s_dead[qd]) <= n) break;
        float4 a0 = s_list[n*3+0];       // mx,my,A2n,B2n (broadcast)
        float4 a1 = s_list[n*3+1];       // C2n,K,cr,cg
        float cb  = s_list[n*3+2].x;
        float dx = px - a0.x;
        float dy = py - a0.y;
        float sg = fmaf(a0.z*dx, dx, a1.y);
        sg = fmaf(a0.w*dx, dy, sg);
        sg = fmaf(a1.x*dy, dy, sg);
        float al = __builtin_amdgcn_exp2f(sg);
        al = (al < ALPHA_MIN_F) ? 0.f : al;
        float w = T*al;
        rr += w*a1.z; gg += w*a1.w; bb += w*cb; T -= w;
        if (__ballot(T > T_EPS) == 0ull) {   // all 64 px saturated in this segment
            if (lane == 0) atomicMin(&s_dead[qd], n);
            break;
        }
    }
    s_part[wv][lane] = make_float4(rr, gg, bb, T);
    __syncthreads();

    // ---- Phase C: in-order reduce of 4 segments per quadrant ----
    if (wv < 4) {                        // wave wv reduces quadrant wv
        float R=0.f, G=0.f, B=0.f, Tt=1.f;
        #pragma unroll
        for (int s = 0; s < 4; ++s) {
            float4 v = s_part[(s << 2) | wv][lane];
            R += Tt*v.x; G += Tt*v.y; B += Tt*v.z; Tt *= v.w;
        }
        const int y = y0 + wv*4 + (lane >> 4);
        const int x = x0 + (lane & 15);
        const int pix = y*WW + x;
        out[pix*3+0] = R; out[pix*3+1] = G; out[pix*3+2] = B;
    }
}

extern "C" void kernel_launch(void* const* d_in, const int* in_sizes, int n_in,
                              void* d_out, int out_size, void* d_ws, size_t ws_size,
                              hipStream_t stream) {
    // d_in: 0=coords (unused by reference), 1=means, 2=quats, 3=scales, 4=opacities, 5=rgbs
    const float* means  = (const float*)d_in[1];
    const float* quats  = (const float*)d_in[2];
    const float* scales = (const float*)d_in[3];
    const float* opac   = (const float*)d_in[4];
    const float* rgbs   = (const float*)d_in[5];
    float* params = (float*)d_ws;                 // NROWS*PR floats = 36 KB

    gs_prep<<<3, 256, 0, stream>>>(means, quats, scales, opac, rgbs, params);
    gs_composite<<<256, 1024, 0, stream>>>(params, (float*)d_out);
}

// Round 8
// 111.525 us; speedup vs baseline: 1.0731x; 1.0731x over previous
//
#include <hip/hip_runtime.h>
#include <math.h>

#define HH 256
#define WW 256
#define NG 714
#define NROWS 768          // padded to 3x256 prep grid; pad rows always culled
#define NGP4 716           // s_tz padded for float4 rank loop
#define SEG 46
#define NSEG 16            // 16 segments x 46 rows = 736 (>= NG)
#define FOCALF 128.0f
#define EPS2D_F 0.3f
#define ALPHA_MIN_F (1.0f/255.0f)
#define CAM_T_F 8.0f
#define LOG2E_F 1.4426950408889634f
#define PR 12              // floats/row: [mx,my,A2n,B2n][C2n,K,cr,cg][cb,e,f,thr]
#define T_EPS 0.003f       // early-termination bound (error <= eps per channel)

// Kernel 1: projection + conic + stable depth rank + scatter into sorted rows.
// Conic stored NEGATED, prefolded with log2(e); K = log2(op) folded additively:
// sg = A2n*dx^2 + B2n*dx*dy + C2n*dy^2 + K  ->  alpha = exp2(sg) = op*exp(-sigma).
// Cull fields: e = C-B^2/4A, f = A-B^2/4C (positive conic, >=0);
// gaussian irrelevant for a box iff max(e*dymin^2, f*dxmin^2) > thr = log2(255)+K
// (then alpha < 1/255 for EVERY pixel in the box -> reference zeroes it: EXACT cull).
__global__ __launch_bounds__(256) void gs_prep(
    const float* __restrict__ means, const float* __restrict__ quats,
    const float* __restrict__ scales, const float* __restrict__ opacities,
    const float* __restrict__ rgbs, float* __restrict__ params)
{
    __shared__ float s_tz[NGP4];
    const int lane = threadIdx.x;
    const int i = blockIdx.x * 256 + lane;

    for (int j = lane; j < NGP4; j += 256)
        s_tz[j] = (j < NG) ? (means[3*j+2] + CAM_T_F) : INFINITY;
    __syncthreads();

    if (i >= NROWS) return;
    if (i >= NG) {                      // pad rows: always culled (0 > thr=-1)
        float4* row = (float4*)(params + i*PR);
        row[0] = make_float4(0.f,0.f,0.f,0.f);
        row[1] = make_float4(0.f,0.f,0.f,0.f);
        row[2] = make_float4(0.f,0.f,0.f,-1.f);
        return;
    }

    float m0 = means[i*3+0], m1 = means[i*3+1];
    float tz = s_tz[i];
    float qw = quats[i*4+0], qx = quats[i*4+1], qy = quats[i*4+2], qz = quats[i*4+3];
    float qn = rsqrtf(qw*qw + qx*qx + qy*qy + qz*qz);
    qw*=qn; qx*=qn; qy*=qn; qz*=qn;
    float sx = scales[i*3+0], sy = scales[i*3+1], sz = scales[i*3+2];
    float s0 = sx*sx, s1 = sy*sy, s2 = sz*sz;
    float R00 = 1.f-2.f*(qy*qy+qz*qz), R01 = 2.f*(qx*qy-qw*qz), R02 = 2.f*(qx*qz+qw*qy);
    float R10 = 2.f*(qx*qy+qw*qz),     R11 = 1.f-2.f*(qx*qx+qz*qz), R12 = 2.f*(qy*qz-qw*qx);
    float R20 = 2.f*(qx*qz-qw*qy),     R21 = 2.f*(qy*qz+qw*qx),     R22 = 1.f-2.f*(qx*qx+qy*qy);
    float S00 = R00*R00*s0 + R01*R01*s1 + R02*R02*s2;
    float S01 = R00*R10*s0 + R01*R11*s1 + R02*R12*s2;
    float S02 = R00*R20*s0 + R01*R21*s1 + R02*R22*s2;
    float S11 = R10*R10*s0 + R11*R11*s1 + R12*R12*s2;
    float S12 = R10*R20*s0 + R11*R21*s1 + R12*R22*s2;
    float S22 = R20*R20*s0 + R21*R21*s1 + R22*R22*s2;
    float inv = 1.f/tz;
    float mx = FOCALF*m0*inv + 0.5f*WW;
    float my = FOCALF*m1*inv + 0.5f*HH;
    float j0 = FOCALF*inv;
    float j2 = -FOCALF*m0*inv*inv;
    float j5 = -FOCALF*m1*inv*inv;
    float a = j0*j0*S00 + 2.f*j0*j2*S02 + j2*j2*S22 + EPS2D_F;
    float b = j0*(j0*S01 + j2*S12) + j5*(j0*S02 + j2*S22);
    float c = j0*j0*S11 + 2.f*j0*j5*S12 + j5*j5*S22 + EPS2D_F;
    float det = a*c - b*b;
    float idet = 1.f/det;
    float hA = 0.5f*c*idet*LOG2E_F;      // positive conic terms (log2-scaled)
    float Bc = -b*idet*LOG2E_F;
    float hC = 0.5f*a*idet*LOG2E_F;
    float e  = hC - Bc*Bc/(4.f*hA);      // min over dx of sigma' = e*dy^2
    float f  = hA - Bc*Bc/(4.f*hC);      // min over dy of sigma' = f*dx^2
    float op = 1.f/(1.f+__expf(-opacities[i]));
    float K  = log2f(op);                // folded into exponent
    float thr = log2f(255.f) + K;        // cull iff bound > thr
    float cr = 1.f/(1.f+__expf(-rgbs[i*3+0]));
    float cg = 1.f/(1.f+__expf(-rgbs[i*3+1]));
    float cb = 1.f/(1.f+__expf(-rgbs[i*3+2]));

    const float4* t4 = (const float4*)s_tz;
    int rank = 0;
    #pragma unroll 4
    for (int jj = 0; jj < NGP4/4; ++jj) {
        float4 v = t4[jj];
        int j = 4*jj;
        rank += (v.x < tz) || (v.x == tz && (j+0) < i);
        rank += (v.y < tz) || (v.y == tz && (j+1) < i);
        rank += (v.z < tz) || (v.z == tz && (j+2) < i);
        rank += (v.w < tz) || (v.w == tz && (j+3) < i);
    }

    float4* row = (float4*)(params + rank*PR);
    row[0] = make_float4(mx, my, -hA, -Bc);
    row[1] = make_float4(-hC, K, cr, cg);
    row[2] = make_float4(cb, e, f, thr);
}

// Kernel 2: compositing. Block = one 16x16 tile, 16 waves = 16 depth segments.
// Thread = 4 CONTIGUOUS rows at one x (64 lanes = 16 x * 4 row-groups -> wave
// covers the whole tile). Square cull box (half-span 7.5,7.5). Params via
// wave-uniform s_load with distance-2 register prefetch. Cross-segment early
// termination: a wave whose local T collapses (< T_EPS on all 256 px) proves
// true T < T_EPS for the tile at that absolute row -> publishes to s_dead;
// all segment-waves poll every 4th iter and abort (error <= T_EPS/channel).
__global__ __launch_bounds__(1024, 1) void gs_composite(
    const float* __restrict__ params, float* __restrict__ out)
{
    __shared__ float4 part[4][NSEG][64];    // [row k][seg][tx] = 64 KB
    __shared__ int s_dead;
    const int tx = threadIdx.x;             // 0..63
    const int seg = __builtin_amdgcn_readfirstlane((int)threadIdx.y);
    const int x0 = (blockIdx.x & 15) * 16;
    const int y0 = (blockIdx.x >> 4) * 16;
    const float px   = (float)(x0 + (tx & 15)) + 0.5f;
    const float yb   = (float)(y0 + ((tx >> 4) << 2)) + 0.5f;   // row-group base
    const float xc   = (float)x0 + 8.0f;    // box center, half-span 7.5
    const float ycen = (float)y0 + 8.0f;
    const int n0 = seg * SEG;

    if (tx == 0 && seg == 0) s_dead = 0x7fffffff;
    __syncthreads();

    const float4* p = ((const float4*)params) + 3*n0;
    float4 a0=p[0], a1=p[1], a2=p[2];
    float4 b0=p[3], b1=p[4], b2=p[5];

    float T0=1.f,r0=0.f,g0=0.f,bl0=0.f;
    float T1=1.f,r1=0.f,g1=0.f,bl1=0.f;
    float T2=1.f,r2=0.f,g2=0.f,bl2=0.f;
    float T3=1.f,r3=0.f,g3=0.f,bl3=0.f;

    for (int n = 0; n < SEG; ++n) {
        if ((n & 3) == 0) {                     // cheap cross-segment poll
            int d = *(volatile int*)&s_dead;
            if (__builtin_amdgcn_readfirstlane(d) <= n0 + n) break;
        }
        float4 c0=p[6], c1=p[7], c2=p[8]; p += 3;   // prefetch n+2 (pads cover tail)
        float dyc = fabsf(ycen - a0.y);
        float dymin = fmaxf(dyc - 7.5f, 0.f);
        float dxc = fabsf(xc - a0.x);
        float dxmin = fmaxf(dxc - 7.5f, 0.f);
        float m = fmaxf(a2.y*dymin*dymin, a2.z*dxmin*dxmin);
        if (!(m > a2.w)) {                          // wave-uniform branch
            float dy0 = yb - a0.y;
            float dy1 = dy0 + 1.f, dy2 = dy0 + 2.f, dy3 = dy0 + 3.f;
            float dx  = px - a0.x;
            float axx = fmaf(a0.z*dx, dx, a1.y);    // A2n*dx^2 + K
            float bdx = a0.w*dx;

            float sg0 = fmaf(bdx, dy0, fmaf(a1.x*dy0, dy0, axx));
            float al0 = __builtin_amdgcn_exp2f(sg0);
            al0 = (al0 < ALPHA_MIN_F) ? 0.f : al0;
            float w0 = T0*al0; r0 += w0*a1.z; g0 += w0*a1.w; bl0 += w0*a2.x; T0 -= w0;

            float sg1 = fmaf(bdx, dy1, fmaf(a1.x*dy1, dy1, axx));
            float al1 = __builtin_amdgcn_exp2f(sg1);
            al1 = (al1 < ALPHA_MIN_F) ? 0.f : al1;
            float w1 = T1*al1; r1 += w1*a1.z; g1 += w1*a1.w; bl1 += w1*a2.x; T1 -= w1;

            float sg2 = fmaf(bdx, dy2, fmaf(a1.x*dy2, dy2, axx));
            float al2 = __builtin_amdgcn_exp2f(sg2);
            al2 = (al2 < ALPHA_MIN_F) ? 0.f : al2;
            float w2 = T2*al2; r2 += w2*a1.z; g2 += w2*a1.w; bl2 += w2*a2.x; T2 -= w2;

            float sg3 = fmaf(bdx, dy3, fmaf(a1.x*dy3, dy3, axx));
            float al3 = __builtin_amdgcn_exp2f(sg3);
            al3 = (al3 < ALPHA_MIN_F) ? 0.f : al3;
            float w3 = T3*al3; r3 += w3*a1.z; g3 += w3*a1.w; bl3 += w3*a2.x; T3 -= w3;

            // local T bounds true T from above: publish tile-wide kill row
            float tmax = fmaxf(fmaxf(T0,T1), fmaxf(T2,T3));
            if (__ballot(tmax > T_EPS) == 0ull) {
                if (tx == 0) atomicMin(&s_dead, n0 + n);
                break;
            }
        }
        a0=b0; a1=b1; a2=b2;
        b0=c0; b1=c1; b2=c2;
    }

    part[0][seg][tx] = make_float4(r0,g0,bl0,T0);
    part[1][seg][tx] = make_float4(r1,g1,bl1,T1);
    part[2][seg][tx] = make_float4(r2,g2,bl2,T2);
    part[3][seg][tx] = make_float4(r3,g3,bl3,T3);
    __syncthreads();

    if (threadIdx.y < 4) {                  // 4 waves, one row of each bundle
        const int k = threadIdx.y;
        float R=0.f,G=0.f,B=0.f,T=1.f;
        #pragma unroll
        for (int s = 0; s < NSEG; ++s) {
            float4 v = part[k][s][tx];
            R += T*v.x; G += T*v.y; B += T*v.z; T *= v.w;
        }
        const int y = y0 + ((tx >> 4) << 2) + k;
        const int x = x0 + (tx & 15);
        const int pix = y*WW + x;
        out[pix*3+0] = R; out[pix*3+1] = G; out[pix*3+2] = B;
    }
}

extern "C" void kernel_launch(void* const* d_in, const int* in_sizes, int n_in,
                              void* d_out, int out_size, void* d_ws, size_t ws_size,
                              hipStream_t stream) {
    // d_in: 0=coords (unused by reference), 1=means, 2=quats, 3=scales, 4=opacities, 5=rgbs
    const float* means  = (const float*)d_in[1];
    const float* quats  = (const float*)d_in[2];
    const float* scales = (const float*)d_in[3];
    const float* opac   = (const float*)d_in[4];
    const float* rgbs   = (const float*)d_in[5];
    float* params = (float*)d_ws;                 // NROWS*PR floats = 36 KB

    gs_prep<<<3, 256, 0, stream>>>(means, quats, scales, opac, rgbs, params);
    gs_composite<<<256, dim3(64, NSEG), 0, stream>>>(params, (float*)d_out);
}

// Round 9
// 104.684 us; speedup vs baseline: 1.1433x; 1.0653x over previous
//
#include <hip/hip_runtime.h>
#include <math.h>

#define HH 256
#define WW 256
#define NG 714
#define NROWS 768          // padded to 3x256 prep grid; pad rows always culled
#define NGP4 716           // s_tz padded for float4 rank loop
#define SEG 46             // rows per wave sub-segment
#define FOCALF 128.0f
#define EPS2D_F 0.3f
#define ALPHA_MIN_F (1.0f/255.0f)
#define CAM_T_F 8.0f
#define LOG2E_F 1.4426950408889634f
#define PR 12              // floats/row: [mx,my,A2n,B2n][C2n,K,cr,cg][cb,e,f,thr]
#define T_EPS 0.003f       // in-wave early-break bound (error <= eps per channel)
#define NPX 65536

// Kernel 1: projection + conic + stable depth rank + scatter into sorted rows.
// Conic stored NEGATED, prefolded with log2(e); K = log2(op) folded additively:
// sg = A2n*dx^2 + B2n*dx*dy + C2n*dy^2 + K  ->  alpha = exp2(sg) = op*exp(-sigma).
// Cull fields: e = C-B^2/4A, f = A-B^2/4C (positive conic, >=0);
// gaussian irrelevant for a box iff max(e*dymin^2, f*dxmin^2) > thr = log2(255)+K
// (then alpha < 1/255 for EVERY pixel in the box -> reference zeroes it: EXACT cull).
__global__ __launch_bounds__(256) void gs_prep(
    const float* __restrict__ means, const float* __restrict__ quats,
    const float* __restrict__ scales, const float* __restrict__ opacities,
    const float* __restrict__ rgbs, float* __restrict__ params)
{
    __shared__ float s_tz[NGP4];
    const int lane = threadIdx.x;
    const int i = blockIdx.x * 256 + lane;

    for (int j = lane; j < NGP4; j += 256)
        s_tz[j] = (j < NG) ? (means[3*j+2] + CAM_T_F) : INFINITY;
    __syncthreads();

    if (i >= NROWS) return;
    if (i >= NG) {                      // pad rows: always culled (0 > thr=-1)
        float4* row = (float4*)(params + i*PR);
        row[0] = make_float4(0.f,0.f,0.f,0.f);
        row[1] = make_float4(0.f,0.f,0.f,0.f);
        row[2] = make_float4(0.f,0.f,0.f,-1.f);
        return;
    }

    float m0 = means[i*3+0], m1 = means[i*3+1];
    float tz = s_tz[i];
    float qw = quats[i*4+0], qx = quats[i*4+1], qy = quats[i*4+2], qz = quats[i*4+3];
    float qn = rsqrtf(qw*qw + qx*qx + qy*qy + qz*qz);
    qw*=qn; qx*=qn; qy*=qn; qz*=qn;
    float sx = scales[i*3+0], sy = scales[i*3+1], sz = scales[i*3+2];
    float s0 = sx*sx, s1 = sy*sy, s2 = sz*sz;
    float R00 = 1.f-2.f*(qy*qy+qz*qz), R01 = 2.f*(qx*qy-qw*qz), R02 = 2.f*(qx*qz+qw*qy);
    float R10 = 2.f*(qx*qy+qw*qz),     R11 = 1.f-2.f*(qx*qx+qz*qz), R12 = 2.f*(qy*qz-qw*qx);
    float R20 = 2.f*(qx*qz-qw*qy),     R21 = 2.f*(qy*qz+qw*qx),     R22 = 1.f-2.f*(qx*qx+qy*qy);
    float S00 = R00*R00*s0 + R01*R01*s1 + R02*R02*s2;
    float S01 = R00*R10*s0 + R01*R11*s1 + R02*R12*s2;
    float S02 = R00*R20*s0 + R01*R21*s1 + R02*R22*s2;
    float S11 = R10*R10*s0 + R11*R11*s1 + R12*R12*s2;
    float S12 = R10*R20*s0 + R11*R21*s1 + R12*R22*s2;
    float S22 = R20*R20*s0 + R21*R21*s1 + R22*R22*s2;
    float inv = 1.f/tz;
    float mx = FOCALF*m0*inv + 0.5f*WW;
    float my = FOCALF*m1*inv + 0.5f*HH;
    float j0 = FOCALF*inv;
    float j2 = -FOCALF*m0*inv*inv;
    float j5 = -FOCALF*m1*inv*inv;
    float a = j0*j0*S00 + 2.f*j0*j2*S02 + j2*j2*S22 + EPS2D_F;
    float b = j0*(j0*S01 + j2*S12) + j5*(j0*S02 + j2*S22);
    float c = j0*j0*S11 + 2.f*j0*j5*S12 + j5*j5*S22 + EPS2D_F;
    float det = a*c - b*b;
    float idet = 1.f/det;
    float hA = 0.5f*c*idet*LOG2E_F;      // positive conic terms (log2-scaled)
    float Bc = -b*idet*LOG2E_F;
    float hC = 0.5f*a*idet*LOG2E_F;
    float e  = hC - Bc*Bc/(4.f*hA);      // min over dx of sigma' = e*dy^2
    float f  = hA - Bc*Bc/(4.f*hC);      // min over dy of sigma' = f*dx^2
    float op = 1.f/(1.f+__expf(-opacities[i]));
    float K  = log2f(op);                // folded into exponent
    float thr = log2f(255.f) + K;        // cull iff bound > thr
    float cr = 1.f/(1.f+__expf(-rgbs[i*3+0]));
    float cg = 1.f/(1.f+__expf(-rgbs[i*3+1]));
    float cb = 1.f/(1.f+__expf(-rgbs[i*3+2]));

    const float4* t4 = (const float4*)s_tz;
    int rank = 0;
    #pragma unroll 4
    for (int jj = 0; jj < NGP4/4; ++jj) {
        float4 v = t4[jj];
        int j = 4*jj;
        rank += (v.x < tz) || (v.x == tz && (j+0) < i);
        rank += (v.y < tz) || (v.y == tz && (j+1) < i);
        rank += (v.z < tz) || (v.z == tz && (j+2) < i);
        rank += (v.w < tz) || (v.w == tz && (j+3) < i);
    }

    float4* row = (float4*)(params + rank*PR);
    row[0] = make_float4(mx, my, -hA, -Bc);
    row[1] = make_float4(-hC, K, cr, cg);
    row[2] = make_float4(cb, e, f, thr);
}

// Kernel 2: compositing, block-level depth split for load balance.
// 1024 blocks = 256 tiles (16x16 px) x 4 depth quarters; blockIdx = tile*4+qtr
// so a hot tile's quarters land on consecutive dispatch slots -> distinct CUs.
// Block = 4 waves = 4 sub-segments (46 rows) of the quarter; thread = 4
// contiguous rows at one x. Params via wave-uniform s_load + distance-2
// register prefetch; square cull box (7.5,7.5); register-only ballot early
// break (bounded error < T_EPS). In-block LDS reduce -> one float4 (R,G,B,T)
// quarter-partial per pixel into ws (L2-resident).
__global__ __launch_bounds__(256, 4) void gs_composite(
    const float* __restrict__ params, float4* __restrict__ qpart)
{
    __shared__ float4 part[4][4][64];       // [wave][row k][tx] = 16 KB
    const int tx = threadIdx.x;             // 0..63
    const int wv = __builtin_amdgcn_readfirstlane((int)threadIdx.y);
    const int tile = blockIdx.x >> 2;
    const int qtr  = blockIdx.x & 3;
    const int x0 = (tile & 15) * 16;
    const int y0 = (tile >> 4) * 16;
    const float px   = (float)(x0 + (tx & 15)) + 0.5f;
    const float yb   = (float)(y0 + ((tx >> 4) << 2)) + 0.5f;   // row-group base
    const float xc   = (float)x0 + 8.0f;    // box center, half-span 7.5
    const float ycen = (float)y0 + 8.0f;
    const int n0 = (qtr*4 + wv) * SEG;      // wave's sub-segment start

    const float4* p = ((const float4*)params) + 3*n0;
    float4 a0=p[0], a1=p[1], a2=p[2];
    float4 b0=p[3], b1=p[4], b2=p[5];

    float T0=1.f,r0=0.f,g0=0.f,bl0=0.f;
    float T1=1.f,r1=0.f,g1=0.f,bl1=0.f;
    float T2=1.f,r2=0.f,g2=0.f,bl2=0.f;
    float T3=1.f,r3=0.f,g3=0.f,bl3=0.f;

    for (int n = 0; n < SEG; ++n) {
        float4 c0=p[6], c1=p[7], c2=p[8]; p += 3;   // prefetch n+2 (pads cover tail)
        float dymin = fmaxf(fabsf(ycen - a0.y) - 7.5f, 0.f);
        float dxmin = fmaxf(fabsf(xc - a0.x) - 7.5f, 0.f);
        float m = fmaxf(a2.y*dymin*dymin, a2.z*dxmin*dxmin);
        if (!(m > a2.w)) {                          // wave-uniform branch
            float dy0 = yb - a0.y;
            float dy1 = dy0 + 1.f, dy2 = dy0 + 2.f, dy3 = dy0 + 3.f;
            float dx  = px - a0.x;
            float axx = fmaf(a0.z*dx, dx, a1.y);    // A2n*dx^2 + K
            float bdx = a0.w*dx;

            float sg0 = fmaf(bdx, dy0, fmaf(a1.x*dy0, dy0, axx));
            float al0 = __builtin_amdgcn_exp2f(sg0);
            al0 = (al0 < ALPHA_MIN_F) ? 0.f : al0;
            float w0 = T0*al0; r0 += w0*a1.z; g0 += w0*a1.w; bl0 += w0*a2.x; T0 -= w0;

            float sg1 = fmaf(bdx, dy1, fmaf(a1.x*dy1, dy1, axx));
            float al1 = __builtin_amdgcn_exp2f(sg1);
            al1 = (al1 < ALPHA_MIN_F) ? 0.f : al1;
            float w1 = T1*al1; r1 += w1*a1.z; g1 += w1*a1.w; bl1 += w1*a2.x; T1 -= w1;

            float sg2 = fmaf(bdx, dy2, fmaf(a1.x*dy2, dy2, axx));
            float al2 = __builtin_amdgcn_exp2f(sg2);
            al2 = (al2 < ALPHA_MIN_F) ? 0.f : al2;
            float w2 = T2*al2; r2 += w2*a1.z; g2 += w2*a1.w; bl2 += w2*a2.x; T2 -= w2;

            float sg3 = fmaf(bdx, dy3, fmaf(a1.x*dy3, dy3, axx));
            float al3 = __builtin_amdgcn_exp2f(sg3);
            al3 = (al3 < ALPHA_MIN_F) ? 0.f : al3;
            float w3 = T3*al3; r3 += w3*a1.z; g3 += w3*a1.w; bl3 += w3*a2.x; T3 -= w3;

            // register-only early break (local T bounds true T from above)
            float tmax = fmaxf(fmaxf(T0,T1), fmaxf(T2,T3));
            if (__ballot(tmax > T_EPS) == 0ull) break;
        }
        a0=b0; a1=b1; a2=b2;
        b0=c0; b1=c1; b2=c2;
    }

    part[wv][0][tx] = make_float4(r0,g0,bl0,T0);
    part[wv][1][tx] = make_float4(r1,g1,bl1,T1);
    part[wv][2][tx] = make_float4(r2,g2,bl2,T2);
    part[wv][3][tx] = make_float4(r3,g3,bl3,T3);
    __syncthreads();

    {   // wave k reduces pixel-row k of each thread's 4-row bundle, in depth order
        const int k = wv;
        float R=0.f,G=0.f,B=0.f,T=1.f;
        #pragma unroll
        for (int s = 0; s < 4; ++s) {
            float4 v = part[s][k][tx];
            R += T*v.x; G += T*v.y; B += T*v.z; T *= v.w;
        }
        const int y = y0 + ((tx >> 4) << 2) + k;
        const int x = x0 + (tx & 15);
        qpart[qtr*NPX + y*WW + x] = make_float4(R,G,B,T);
    }
}

// Kernel 3: fold the 4 depth-quarter partials in order.
__global__ __launch_bounds__(256) void gs_combine(
    const float4* __restrict__ qpart, float* __restrict__ out)
{
    const int px = blockIdx.x*256 + threadIdx.x;
    float4 p0 = qpart[px];
    float4 p1 = qpart[NPX + px];
    float4 p2 = qpart[2*NPX + px];
    float4 p3 = qpart[3*NPX + px];
    out[px*3+0] = p0.x + p0.w*(p1.x + p1.w*(p2.x + p2.w*p3.x));
    out[px*3+1] = p0.y + p0.w*(p1.y + p1.w*(p2.y + p2.w*p3.y));
    out[px*3+2] = p0.z + p0.w*(p1.z + p1.w*(p2.z + p2.w*p3.z));
}

extern "C" void kernel_launch(void* const* d_in, const int* in_sizes, int n_in,
                              void* d_out, int out_size, void* d_ws, size_t ws_size,
                              hipStream_t stream) {
    // d_in: 0=coords (unused by reference), 1=means, 2=quats, 3=scales, 4=opacities, 5=rgbs
    const float* means  = (const float*)d_in[1];
    const float* quats  = (const float*)d_in[2];
    const float* scales = (const float*)d_in[3];
    const float* opac   = (const float*)d_in[4];
    const float* rgbs   = (const float*)d_in[5];

    char* ws = (char*)d_ws;
    float*  params = (float*)ws;                    // NROWS*PR floats = 36 KB
    float4* qpart  = (float4*)(ws + (64<<10));      // 4*65536*16 B = 4 MB

    gs_prep<<<3, 256, 0, stream>>>(means, quats, scales, opac, rgbs, params);
    gs_composite<<<1024, dim3(64,4), 0, stream>>>(params, qpart);
    gs_combine<<<NPX/256, 256, 0, stream>>>(qpart, (float*)d_out);
}